// Round 2
// baseline (2836.652 us; speedup 1.0000x reference)
//
#include <hip/hip_runtime.h>
#include <cstdint>
#include <cstddef>

#define H_IMG 256
#define W_IMG 320
#define HW_IMG (H_IMG * W_IMG)   // 81920
#define NCLS 22
#define VOTE_STEPS 160

// ---------------------------------------------------------------------------
// Weight repack: w[cin][cout][4][4] (torch ConvTranspose layout) ->
// wp[pp][cin][cout][4], pp = ry*2+rx output parity, tap j = dy*2+dx maps to
// original (ky,kx) = (3-ry-2dy, 3-rx-2dx). Stored f32 (exact; cast on use).
// ---------------------------------------------------------------------------
__global__ void repack_kernel(const float* __restrict__ w, float* __restrict__ wp,
                              int CIN, int COUT) {
    int total = CIN * COUT * 16;
    for (int i = blockIdx.x * blockDim.x + threadIdx.x; i < total;
         i += gridDim.x * blockDim.x) {
        int j = i & 3;
        int co = (i >> 2) % COUT;
        int rest = (i >> 2) / COUT;   // pp*CIN + cin
        int cin = rest % CIN;
        int pp = rest / CIN;
        int ry = pp >> 1, rx = pp & 1;
        int dy = j >> 1, dx = j & 1;
        int ky = 3 - ry - 2 * dy;
        int kx = 3 - rx - 2 * dx;
        wp[i] = w[((size_t)cin * COUT + co) * 16 + ky * 4 + kx];
    }
}

// w[O][K] -> wt[K][O]
__global__ void transpose_kernel(const float* __restrict__ w, float* __restrict__ wt,
                                 int O, int K) {
    int i = blockIdx.x * blockDim.x + threadIdx.x;
    if (i < O * K) {
        int o = i / K, k = i - o * K;
        wt[k * O + o] = w[i];
    }
}

__global__ void bias_init_d_kernel(double* __restrict__ out,
                                   const float* __restrict__ bias,
                                   int COUT, int HWo, int total) {
    for (int i = blockIdx.x * blockDim.x + threadIdx.x; i < total;
         i += gridDim.x * blockDim.x) {
        out[i] = (double)bias[(i / HWo) % COUT];
    }
}

// ---------------------------------------------------------------------------
// ConvTranspose2d(k=4,s=2,p=1), fp64 accumulation/storage.
// Grid: x = pixel tiles of one parity plane, y = (COUT/NCO)*4 (cog*4+parity),
// z = B*nSplit. inA is double (prev layer, ADBL=1) or float (x1, ADBL=0);
// inB is always a float skip input. ATOMIC: cin-chunk partial accumulated
// via f64 atomics onto a bias-initialized buffer.
// ---------------------------------------------------------------------------
template <int NCO, bool RELU_A, bool ATOMIC, bool ADBL>
__global__ __launch_bounds__(256) void convt_d_kernel(
    const void* __restrict__ inA_, int CA,
    const float* __restrict__ inB, int CB,
    const float* __restrict__ wp,   // [4][CIN][COUT][4] f32
    const float* __restrict__ bias,
    double* __restrict__ out,
    int COUT, int Hin, int Win, int nSplit, int B) {
    const int CIN = CA + CB;
    const int cog = blockIdx.y >> 2;
    const int pp = blockIdx.y & 3;
    const int ry = pp >> 1, rx = pp & 1;
    const int b = blockIdx.z % B;
    const int sp = blockIdx.z / B;
    const int cinPer = CIN / nSplit;
    const int c0 = sp * cinPer, c1 = c0 + cinPer;
    const int co0 = cog * NCO;
    const int plane = Hin * Win;
    const int Hout = Hin * 2, Wout = Win * 2;

    for (int p = blockIdx.x * 256 + threadIdx.x; p < plane; p += gridDim.x * 256) {
        int m = p / Win, n = p - m * Win;
        int iy0 = m + ry - 1, ix0 = n + rx - 1;
        int oy = 2 * m + ry, ox = 2 * n + rx;
        double f00 = (iy0 >= 0 && ix0 >= 0) ? 1.0 : 0.0;
        double f01 = (iy0 >= 0 && ix0 + 1 < Win) ? 1.0 : 0.0;
        double f10 = (iy0 + 1 < Hin && ix0 >= 0) ? 1.0 : 0.0;
        double f11 = (iy0 + 1 < Hin && ix0 + 1 < Win) ? 1.0 : 0.0;
        int cy0 = max(iy0, 0), cy1 = min(iy0 + 1, Hin - 1);
        int cx0 = max(ix0, 0), cx1 = min(ix0 + 1, Win - 1);
        int o00 = cy0 * Win + cx0, o01 = cy0 * Win + cx1;
        int o10 = cy1 * Win + cx0, o11 = cy1 * Win + cx1;

        double acc[NCO];
#pragma unroll
        for (int k = 0; k < NCO; ++k) acc[k] = ATOMIC ? 0.0 : (double)bias[co0 + k];

        // ---- part A ----
        int a0 = min(c0, CA), a1 = min(c1, CA);
        for (int c = a0; c < a1; ++c) {
            double x00, x01, x10, x11;
            if (ADBL) {
                const double* s = (const double*)inA_ + ((size_t)b * CA + c) * plane;
                x00 = f00 * s[o00]; x01 = f01 * s[o01];
                x10 = f10 * s[o10]; x11 = f11 * s[o11];
            } else {
                const float* s = (const float*)inA_ + ((size_t)b * CA + c) * plane;
                x00 = f00 * (double)s[o00]; x01 = f01 * (double)s[o01];
                x10 = f10 * (double)s[o10]; x11 = f11 * (double)s[o11];
            }
            if (RELU_A) {
                x00 = fmax(x00, 0.0); x01 = fmax(x01, 0.0);
                x10 = fmax(x10, 0.0); x11 = fmax(x11, 0.0);
            }
            const float* wr = wp + (((size_t)pp * CIN + c) * COUT + co0) * 4;
#pragma unroll
            for (int k = 0; k < NCO; ++k)
                acc[k] += x00 * (double)wr[4 * k] + x01 * (double)wr[4 * k + 1] +
                          x10 * (double)wr[4 * k + 2] + x11 * (double)wr[4 * k + 3];
        }
        // ---- part B (skip input, f32) ----
        if (CB > 0) {
            int b0 = max(c0, CA) - CA, b1 = max(c1, CA) - CA;
            const float* srcB = inB + (size_t)b * CB * plane;
            for (int c = b0; c < b1; ++c) {
                const float* s = srcB + (size_t)c * plane;
                double x00 = f00 * (double)s[o00], x01 = f01 * (double)s[o01];
                double x10 = f10 * (double)s[o10], x11 = f11 * (double)s[o11];
                const float* wr = wp + (((size_t)pp * CIN + (c + CA)) * COUT + co0) * 4;
#pragma unroll
                for (int k = 0; k < NCO; ++k)
                    acc[k] += x00 * (double)wr[4 * k] + x01 * (double)wr[4 * k + 1] +
                              x10 * (double)wr[4 * k + 2] + x11 * (double)wr[4 * k + 3];
            }
        }

        size_t ob = ((size_t)b * COUT + co0) * (size_t)Hout * Wout +
                    (size_t)oy * Wout + ox;
#pragma unroll
        for (int k = 0; k < NCO; ++k) {
            if (ATOMIC)
                atomicAdd(&out[ob + (size_t)k * Hout * Wout], acc[k]);
            else
                out[ob + (size_t)k * Hout * Wout] = acc[k];
        }
    }
}

// ---------------------------------------------------------------------------
// Heads (fp64): vertex (66 ch -> f32 out; ch0/1 also saved f64 for voting)
// and logits (22 ch -> argmax label).
// ---------------------------------------------------------------------------
__global__ __launch_bounds__(256) void vertex_d_kernel(
    const double* __restrict__ z5, const float* __restrict__ wvT,  // [64][66]
    const float* __restrict__ bv, float* __restrict__ vert,
    double* __restrict__ dirs) {
    int p = blockIdx.x * 256 + threadIdx.x;
    int cog = blockIdx.y;   // 0..2 -> 22 channels each
    int b = blockIdx.z;
    const int O = 66;
    int co0 = cog * 22;
    double acc[22];
#pragma unroll
    for (int k = 0; k < 22; ++k) acc[k] = (double)bv[co0 + k];
    const double* xp = z5 + (size_t)b * 64 * HW_IMG + p;
    for (int c = 0; c < 64; ++c) {
        double x = fmax(xp[(size_t)c * HW_IMG], 0.0);
        const float* w = wvT + c * O + co0;
#pragma unroll
        for (int k = 0; k < 22; ++k) acc[k] += x * (double)w[k];
    }
    float* op = vert + ((size_t)b * O + co0) * HW_IMG + p;
#pragma unroll
    for (int k = 0; k < 22; ++k) op[(size_t)k * HW_IMG] = (float)acc[k];
    if (cog == 0) {
        dirs[(size_t)b * 2 * HW_IMG + p] = acc[0];
        dirs[(size_t)b * 2 * HW_IMG + HW_IMG + p] = acc[1];
    }
}

__global__ __launch_bounds__(256) void logits_d_kernel(
    const double* __restrict__ z5, const float* __restrict__ wcT,  // [64][22]
    const float* __restrict__ bc, float* __restrict__ label) {
    int p = blockIdx.x * 256 + threadIdx.x;
    int b = blockIdx.z;
    double acc[NCLS];
#pragma unroll
    for (int k = 0; k < NCLS; ++k) acc[k] = (double)bc[k];
    const double* xp = z5 + (size_t)b * 64 * HW_IMG + p;
    for (int c = 0; c < 64; ++c) {
        double x = fmax(xp[(size_t)c * HW_IMG], 0.0);
        const float* w = wcT + c * NCLS;
#pragma unroll
        for (int k = 0; k < NCLS; ++k) acc[k] += x * (double)w[k];
    }
    int bi = 0; double bvv = acc[0];
#pragma unroll
    for (int k = 1; k < NCLS; ++k)
        if (acc[k] > bvv) { bvv = acc[k]; bi = k; }   // first max, like np.argmax
    label[(size_t)b * HW_IMG + p] = (float)bi;
}

// ---------------------------------------------------------------------------
// Hough vote (fp64): seg_fused = clip(sum_c seg, 0, 1); if > 0.5, march 160
// unit steps along normalized dir, f64 atomic accumulate. Also masked depth /
// count reduction for translation.
// ---------------------------------------------------------------------------
__global__ __launch_bounds__(256) void vote_d_kernel(
    const float* __restrict__ seg, const float* __restrict__ depth,
    const double* __restrict__ dirs, double* __restrict__ voteacc,
    double* __restrict__ sums) {
    int p = blockIdx.x * 256 + threadIdx.x;
    int b = blockIdx.z;
    double s = 0.0;
    const float* sp = seg + (size_t)b * NCLS * HW_IMG + p;
    for (int c = 0; c < NCLS; ++c) s += (double)sp[(size_t)c * HW_IMG];
    s = fmin(fmax(s, 0.0), 1.0);
    bool msk = s > 0.5;
    double d = (double)depth[(size_t)b * HW_IMG + p];
    double dm = msk ? d : 0.0;
    double mm = msk ? 1.0 : 0.0;
    for (int off = 32; off > 0; off >>= 1) {
        dm += __shfl_down(dm, off);
        mm += __shfl_down(mm, off);
    }
    __shared__ double sdm[4], smm[4];
    int wid = threadIdx.x >> 6, lane = threadIdx.x & 63;
    if (lane == 0) { sdm[wid] = dm; smm[wid] = mm; }
    __syncthreads();
    if (threadIdx.x == 0) {
        atomicAdd(&sums[b * 2 + 0], sdm[0] + sdm[1] + sdm[2] + sdm[3]);
        atomicAdd(&sums[b * 2 + 1], smm[0] + smm[1] + smm[2] + smm[3]);
    }
    if (msk) {
        double dx = dirs[(size_t)b * 2 * HW_IMG + p];
        double dy = dirs[(size_t)b * 2 * HW_IMG + HW_IMG + p];
        double nrm = sqrt(dx * dx + dy * dy) + 1e-6;
        double u = dx / nrm, v = dy / nrm;
        double xf = (double)(p % W_IMG), yf = (double)(p / W_IMG);
        double* vb = voteacc + (size_t)b * HW_IMG;
        for (int t = 1; t <= VOTE_STEPS; ++t) {
            double tf = (double)t;
            int xi = (int)rint(xf + tf * u);   // half-to-even, like np.round
            int yi = (int)rint(yf + tf * v);
            if (xi >= 0 && xi < W_IMG && yi >= 0 && yi < H_IMG)
                atomicAdd(&vb[yi * W_IMG + xi], s);
        }
    }
}

__global__ void vote_cvt_kernel(const double* __restrict__ voteacc,
                                float* __restrict__ vote, int total) {
    int i = blockIdx.x * blockDim.x + threadIdx.x;
    if (i < total) vote[i] = (float)voteacc[i];
}

// One block per batch: vote-map argmax (first-index tie-break) + translation.
__global__ __launch_bounds__(1024) void center_d_kernel(
    const double* __restrict__ voteacc, const double* __restrict__ sums,
    const float* __restrict__ fx, const float* __restrict__ fy,
    const float* __restrict__ px, const float* __restrict__ py,
    float* __restrict__ centers, float* __restrict__ transl) {
    int b = blockIdx.x;
    const double* vb = voteacc + (size_t)b * HW_IMG;
    double best = -1.0;
    int bi = HW_IMG;
    for (int i = threadIdx.x; i < HW_IMG; i += 1024) {
        double v = vb[i];
        if (v > best || (v == best && i < bi)) { best = v; bi = i; }
    }
    for (int off = 32; off > 0; off >>= 1) {
        double ov = __shfl_down(best, off);
        int oi = __shfl_down(bi, off);
        if (ov > best || (ov == best && oi < bi)) { best = ov; bi = oi; }
    }
    __shared__ double sbv[16];
    __shared__ int sbi[16];
    int wid = threadIdx.x >> 6, lane = threadIdx.x & 63;
    if (lane == 0) { sbv[wid] = best; sbi[wid] = bi; }
    __syncthreads();
    if (threadIdx.x == 0) {
        for (int q = 1; q < 16; ++q)
            if (sbv[q] > best || (sbv[q] == best && sbi[q] < bi)) {
                best = sbv[q]; bi = sbi[q];
            }
        double cx = (double)(bi % W_IMG), cy = (double)(bi / W_IMG);
        double tz = sums[b * 2 + 0] / (sums[b * 2 + 1] + 1e-6);
        double tx = (cx - (double)px[0]) * tz / (double)fx[0];
        double ty = (cy - (double)py[0]) * tz / (double)fy[0];
        centers[b * 2 + 0] = (float)cx;
        centers[b * 2 + 1] = (float)cy;
        transl[b * 3 + 0] = (float)tx;
        transl[b * 3 + 1] = (float)ty;
        transl[b * 3 + 2] = (float)tz;
    }
}

// ---------------------------------------------------------------------------
extern "C" void kernel_launch(void* const* d_in, const int* in_sizes, int n_in,
                              void* d_out, int out_size, void* d_ws, size_t ws_size,
                              hipStream_t stream) {
    const float* x1 = (const float*)d_in[0];
    const float* x2 = (const float*)d_in[1];
    const float* x3 = (const float*)d_in[2];
    const float* x4 = (const float*)d_in[3];
    const float* x5 = (const float*)d_in[4];
    const float* depth = (const float*)d_in[5];
    const float* seg = (const float*)d_in[6];
    const float* fx = (const float*)d_in[7];
    const float* fy = (const float*)d_in[8];
    const float* px = (const float*)d_in[9];
    const float* py = (const float*)d_in[10];
    const float* w5 = (const float*)d_in[11];
    const float* b5 = (const float*)d_in[12];
    const float* w4 = (const float*)d_in[13];
    const float* b4 = (const float*)d_in[14];
    const float* w3 = (const float*)d_in[15];
    const float* b3 = (const float*)d_in[16];
    const float* w2 = (const float*)d_in[17];
    const float* b2 = (const float*)d_in[18];
    const float* w1 = (const float*)d_in[19];
    const float* b1 = (const float*)d_in[20];
    const float* wv = (const float*)d_in[21];
    const float* bv = (const float*)d_in[22];
    const float* wc = (const float*)d_in[23];
    const float* bc = (const float*)d_in[24];

    // output layout (flat f32, reference return order)
    float* out = (float*)d_out;
    float* vert = out;                               // [4,66,256,320]
    float* label = vert + (size_t)4 * 66 * HW_IMG;   // [4,256,320]
    float* vote = label + (size_t)4 * HW_IMG;        // [4,256,320]
    float* centers = vote + (size_t)4 * HW_IMG;      // [4,2]
    float* transl = centers + 8;                     // [4,3]

    // workspace layout: doubles first (alignment), then f32 weights.
    // zA holds z1 -> z3 -> z5 ; zB holds z2 -> z4 (chain allows reuse).
    double* zA = (double*)d_ws;            // 20,971,520 f64 (max: z5)
    double* zB = zA + 20971520;            //  5,242,880 f64 (max: z4)
    double* dirs = zB + 5242880;           //    655,360 f64 [4][2][HW]
    double* voteacc = dirs + 655360;       //    327,680 f64 [4][HW]
    double* sums = voteacc + 327680;       //          8 f64
    float* wp5 = (float*)(sums + 8);       // 2,097,152 f32
    float* wp4 = wp5 + 2097152;            // 1,048,576
    float* wp3 = wp4 + 1048576;            //   262,144
    float* wp2 = wp3 + 262144;             //   131,072
    float* wp1 = wp2 + 131072;             //   131,072
    float* wvT = wp1 + 131072;             //     4,224
    float* wcT = wvT + 4224;               //     1,408
    double* z1 = zA; double* z2 = zB; double* z3 = zA; double* z4 = zB; double* z5 = zA;

    hipMemsetAsync(voteacc, 0, (327680 + 8) * sizeof(double), stream);

    // weight repacks
    auto rp = [&](const float* w, float* wp, int CIN, int COUT) {
        int total = CIN * COUT * 16;
        repack_kernel<<<(total + 255) / 256, 256, 0, stream>>>(w, wp, CIN, COUT);
    };
    rp(w5, wp5, 512, 256);
    rp(w4, wp4, 512, 128);
    rp(w3, wp3, 256, 64);
    rp(w2, wp2, 128, 64);
    rp(w1, wp1, 128, 64);
    transpose_kernel<<<(66 * 64 + 255) / 256, 256, 0, stream>>>(wv, wvT, 66, 64);
    transpose_kernel<<<(22 * 64 + 255) / 256, 256, 0, stream>>>(wc, wcT, 22, 64);

    // L1: x1[4,512,8,10] -> z1[4,256,16,20], cin-split 8, atomic
    bias_init_d_kernel<<<(327680 + 255) / 256, 256, 0, stream>>>(z1, b5, 256, 320, 327680);
    convt_d_kernel<16, false, true, false><<<dim3(1, (256 / 16) * 4, 4 * 8), 256, 0, stream>>>(
        x1, 512, nullptr, 0, wp5, b5, z1, 256, 8, 10, 8, 4);
    // L2: [relu(z1)|x2] -> z2[4,128,32,40], split 4
    bias_init_d_kernel<<<(655360 + 255) / 256, 256, 0, stream>>>(z2, b4, 128, 1280, 655360);
    convt_d_kernel<16, true, true, true><<<dim3(2, (128 / 16) * 4, 4 * 4), 256, 0, stream>>>(
        z1, 256, x2, 256, wp4, b4, z2, 128, 16, 20, 4, 4);
    // L3: [relu(z2)|x3] -> z3[4,64,64,80], split 2
    bias_init_d_kernel<<<(1310720 + 255) / 256, 256, 0, stream>>>(z3, b3, 64, 5120, 1310720);
    convt_d_kernel<16, true, true, true><<<dim3(5, (64 / 16) * 4, 4 * 2), 256, 0, stream>>>(
        z2, 128, x3, 128, wp3, b3, z3, 64, 32, 40, 2, 4);
    // L4: [relu(z3)|x4] -> z4[4,64,128,160]
    convt_d_kernel<16, true, false, true><<<dim3(20, (64 / 16) * 4, 4), 256, 0, stream>>>(
        z3, 64, x4, 64, wp2, b2, z4, 64, 64, 80, 1, 4);
    // L5: [relu(z4)|x5] -> z5[4,64,256,320]
    convt_d_kernel<16, true, false, true><<<dim3(80, (64 / 16) * 4, 4), 256, 0, stream>>>(
        z4, 64, x5, 64, wp1, b1, z5, 64, 128, 160, 1, 4);

    // heads
    vertex_d_kernel<<<dim3(320, 3, 4), 256, 0, stream>>>(z5, wvT, bv, vert, dirs);
    logits_d_kernel<<<dim3(320, 1, 4), 256, 0, stream>>>(z5, wcT, bc, label);

    // hough voting
    vote_d_kernel<<<dim3(320, 1, 4), 256, 0, stream>>>(seg, depth, dirs, voteacc, sums);
    vote_cvt_kernel<<<(327680 + 255) / 256, 256, 0, stream>>>(voteacc, vote, 327680);
    center_d_kernel<<<4, 1024, 0, stream>>>(voteacc, sums, fx, fy, px, py, centers, transl);
}